// Round 1
// baseline (827.547 us; speedup 1.0000x reference)
//
#include <hip/hip_runtime.h>
#include <math.h>

// Problem constants
#define Bq 2
#define Sq 2048
#define Cq 768
#define Hq 12
#define Dq 64

// ---------------------------------------------------------------------------
// Kernel 0: RoPE cos/sin tables  [S][32] each, fp64-accurate
// inv[i] = 10000^(-i/32) = exp(-i * ln(10000)/32)
// ---------------------------------------------------------------------------
__global__ void freq_kernel(float* __restrict__ ctab, float* __restrict__ stab) {
    int idx = blockIdx.x * blockDim.x + threadIdx.x;   // 0..65535
    int s = idx >> 5;
    int i = idx & 31;
    double f = (double)s * exp(-(double)i * 0.28782313662425573); // ln(1e4)/32
    ctab[idx] = (float)cos(f);
    stab[idx] = (float)sin(f);
}

// ---------------------------------------------------------------------------
// Tiled fp32 NT GEMM: out[m][n] = sum_k A[m][k] * B[n][k],  K = 768
// 128x128 tile, BK=16, 256 threads, 8x8 micro-tile per thread.
// MODE 0: QKV + fused RoPE -> writes q/k/v in [B,H,S,D] layout
// MODE 1: proj + bias      -> writes [M][768] row-major (= output)
// ---------------------------------------------------------------------------
template <int MODE>
__global__ __launch_bounds__(256) void gemm_kernel(
    const float* __restrict__ A, const float* __restrict__ Bm,
    float* __restrict__ out0, float* __restrict__ out1, float* __restrict__ out2,
    const float* __restrict__ ctab, const float* __restrict__ stab,
    const float* __restrict__ bias)
{
    __shared__ float aT[16][132];   // aT[k][m]
    __shared__ float bT[16][132];   // bT[k][n]

    const int t  = threadIdx.x;
    const int tx = t & 15;          // 0..15 -> n
    const int ty = t >> 4;          // 0..15 -> m
    const int lrow = t >> 1;        // 0..127 (row of tile being loaded)
    const int kq   = (t & 1) * 8;   // 0 or 8

    const int mBase = blockIdx.y * 128;
    const int nBase = blockIdx.x * 128;

    const float* Ap = A  + (mBase + lrow) * Cq + kq;
    const float* Bp = Bm + (nBase + lrow) * Cq + kq;

    float acc[8][8] = {};

    for (int k0 = 0; k0 < Cq; k0 += 16) {
        float4 a0 = *(const float4*)(Ap + k0);
        float4 a1 = *(const float4*)(Ap + k0 + 4);
        float4 b0 = *(const float4*)(Bp + k0);
        float4 b1 = *(const float4*)(Bp + k0 + 4);
        __syncthreads();   // previous compute finished reading LDS
        aT[kq + 0][lrow] = a0.x; aT[kq + 1][lrow] = a0.y;
        aT[kq + 2][lrow] = a0.z; aT[kq + 3][lrow] = a0.w;
        aT[kq + 4][lrow] = a1.x; aT[kq + 5][lrow] = a1.y;
        aT[kq + 6][lrow] = a1.z; aT[kq + 7][lrow] = a1.w;
        bT[kq + 0][lrow] = b0.x; bT[kq + 1][lrow] = b0.y;
        bT[kq + 2][lrow] = b0.z; bT[kq + 3][lrow] = b0.w;
        bT[kq + 4][lrow] = b1.x; bT[kq + 5][lrow] = b1.y;
        bT[kq + 6][lrow] = b1.z; bT[kq + 7][lrow] = b1.w;
        __syncthreads();
        #pragma unroll
        for (int kk = 0; kk < 16; ++kk) {
            float ar[8], br[8];
            *(float4*)&ar[0] = *(const float4*)&aT[kk][ty * 4];
            *(float4*)&ar[4] = *(const float4*)&aT[kk][64 + ty * 4];
            *(float4*)&br[0] = *(const float4*)&bT[kk][tx * 4];
            *(float4*)&br[4] = *(const float4*)&bT[kk][64 + tx * 4];
            #pragma unroll
            for (int i = 0; i < 8; ++i)
                #pragma unroll
                for (int j = 0; j < 8; ++j)
                    acc[i][j] = fmaf(ar[i], br[j], acc[i][j]);
        }
    }

    if (MODE == 0) {
        // which 768-column band: 0 = q, 1 = k, 2 = v (128 | 768 so uniform per block)
        const int which = nBase / Cq;
        float* outb = (which == 0) ? out0 : (which == 1) ? out1 : out2;
        #pragma unroll
        for (int ig = 0; ig < 2; ++ig) {
            #pragma unroll
            for (int jg = 0; jg < 2; ++jg) {
                const int cbase = nBase + jg * 64 + tx * 4;
                const int rem   = cbase - which * Cq;
                const int h     = rem >> 6;
                const int dd    = rem & 63;           // aligned to 4
                #pragma unroll
                for (int i = 0; i < 4; ++i) {
                    const int rg = mBase + ig * 64 + ty * 4 + i;
                    const int bb = rg >> 11;
                    const int ss = rg & 2047;
                    float v0 = acc[ig * 4 + i][jg * 4 + 0];
                    float v1 = acc[ig * 4 + i][jg * 4 + 1];
                    float v2 = acc[ig * 4 + i][jg * 4 + 2];
                    float v3 = acc[ig * 4 + i][jg * 4 + 3];
                    float o0, o1, o2, o3;
                    if (which < 2) {
                        const int fi = ss * 32 + (dd >> 1);
                        float c0 = ctab[fi],     s0 = stab[fi];
                        float c1 = ctab[fi + 1], s1 = stab[fi + 1];
                        o0 = v0 * c0 - v1 * s0;  o1 = v1 * c0 + v0 * s0;
                        o2 = v2 * c1 - v3 * s1;  o3 = v3 * c1 + v2 * s1;
                    } else {
                        o0 = v0; o1 = v1; o2 = v2; o3 = v3;
                    }
                    const int oidx = ((bb * Hq + h) * Sq + ss) * Dq + dd;
                    *(float4*)&outb[oidx] = make_float4(o0, o1, o2, o3);
                }
            }
        }
    } else {
        #pragma unroll
        for (int ig = 0; ig < 2; ++ig) {
            #pragma unroll
            for (int jg = 0; jg < 2; ++jg) {
                const int cbase = nBase + jg * 64 + tx * 4;
                float4 bz = *(const float4*)&bias[cbase];
                #pragma unroll
                for (int i = 0; i < 4; ++i) {
                    const int rg = mBase + ig * 64 + ty * 4 + i;
                    float4 r = make_float4(acc[ig*4+i][jg*4+0] + bz.x,
                                           acc[ig*4+i][jg*4+1] + bz.y,
                                           acc[ig*4+i][jg*4+2] + bz.z,
                                           acc[ig*4+i][jg*4+3] + bz.w);
                    *(float4*)&out0[rg * Cq + cbase] = r;
                }
            }
        }
    }
}

// ---------------------------------------------------------------------------
// Kernel 2: flash-style attention.
// Block = 256 threads = one (b,h) x 64 Q rows. K/V tiles of 64 staged in LDS.
// P tile reuses the dead K-tile LDS (transposed) so PV reads are ds_read_b128.
// Writes softmax(QK^T*scale)@V directly in [B,S,C] layout.
// ---------------------------------------------------------------------------
__global__ __launch_bounds__(256) void attn_kernel(
    const float* __restrict__ qb, const float* __restrict__ kb,
    const float* __restrict__ vb, float* __restrict__ attn)
{
    __shared__ float qT[64][68];    // qT[d][r]
    __shared__ float kpT[64][68];   // kT[d][c] during scores; pT[c][r] during PV
    __shared__ float vS[64][68];    // v[c][d]
    __shared__ float red[64][17];
    __shared__ float mstate[64], lstate[64], alpha_s[64], newm_s[64];

    const int t  = threadIdx.x;
    const int tx = t & 15;          // cols (c for scores, d for PV)
    const int ty = t >> 4;          // rows (q rows)
    const int qt = blockIdx.x;      // 0..31
    const int bh = blockIdx.y;      // 0..23
    const int lr  = t >> 2;         // 0..63  load row
    const int ldc = (t & 3) * 16;   // load col chunk

    const float* qp = qb + ((size_t)bh * Sq + qt * 64) * Dq;
    #pragma unroll
    for (int u = 0; u < 16; u += 4) {
        float4 v = *(const float4*)(qp + lr * 64 + ldc + u);
        qT[ldc + u + 0][lr] = v.x; qT[ldc + u + 1][lr] = v.y;
        qT[ldc + u + 2][lr] = v.z; qT[ldc + u + 3][lr] = v.w;
    }
    if (t < 64) { mstate[t] = -INFINITY; lstate[t] = 0.f; }
    float O[4][4] = {};
    __syncthreads();

    for (int kt = 0; kt < 32; ++kt) {
        const float* kp = kb + ((size_t)bh * Sq + kt * 64) * Dq;
        const float* vp = vb + ((size_t)bh * Sq + kt * 64) * Dq;
        float4 kreg[4], vreg[4];
        #pragma unroll
        for (int u = 0; u < 4; ++u) {
            kreg[u] = *(const float4*)(kp + lr * 64 + ldc + u * 4);
            vreg[u] = *(const float4*)(vp + lr * 64 + ldc + u * 4);
        }
        __syncthreads();    // previous PV done with kpT / vS
        #pragma unroll
        for (int u = 0; u < 4; ++u) {
            kpT[ldc + u * 4 + 0][lr] = kreg[u].x;
            kpT[ldc + u * 4 + 1][lr] = kreg[u].y;
            kpT[ldc + u * 4 + 2][lr] = kreg[u].z;
            kpT[ldc + u * 4 + 3][lr] = kreg[u].w;
            *(float4*)&vS[lr][ldc + u * 4] = vreg[u];
        }
        __syncthreads();

        // ---- scores: sc[i][j] = q[row ty*4+i] . k[col tx*4+j] * scale ----
        float sc[4][4] = {};
        #pragma unroll
        for (int d = 0; d < 64; ++d) {
            float4 qv = *(const float4*)&qT[d][ty * 4];
            float4 kv = *(const float4*)&kpT[d][tx * 4];
            const float* qa = (const float*)&qv;
            const float* ka = (const float*)&kv;
            #pragma unroll
            for (int i = 0; i < 4; ++i)
                #pragma unroll
                for (int j = 0; j < 4; ++j)
                    sc[i][j] = fmaf(qa[i], ka[j], sc[i][j]);
        }
        #pragma unroll
        for (int i = 0; i < 4; ++i) {
            float pm = -INFINITY;
            #pragma unroll
            for (int j = 0; j < 4; ++j) {
                sc[i][j] *= 0.125f;           // 64^-0.5
                pm = fmaxf(pm, sc[i][j]);
            }
            red[ty * 4 + i][tx] = pm;
        }
        __syncthreads();
        if (t < 64) {
            float tm = red[t][0];
            #pragma unroll
            for (int j = 1; j < 16; ++j) tm = fmaxf(tm, red[t][j]);
            float m_old = mstate[t];
            float nm = fmaxf(m_old, tm);
            alpha_s[t] = __expf(m_old - nm);   // 0 on first tile (m_old=-inf)
            newm_s[t]  = nm;
            mstate[t]  = nm;
        }
        __syncthreads();

        // ---- P = exp(sc - m), store transposed pT[c][r], row partial sums ----
        float psum[4] = {0.f, 0.f, 0.f, 0.f};
        #pragma unroll
        for (int j = 0; j < 4; ++j) {
            float4 pj;
            float* pp = (float*)&pj;
            #pragma unroll
            for (int i = 0; i < 4; ++i) {
                float p = __expf(sc[i][j] - newm_s[ty * 4 + i]);
                pp[i] = p;
                psum[i] += p;
            }
            *(float4*)&kpT[tx * 4 + j][ty * 4] = pj;   // pT[c][r]
        }
        #pragma unroll
        for (int i = 0; i < 4; ++i) {
            red[ty * 4 + i][tx] = psum[i];
            float al = alpha_s[ty * 4 + i];
            #pragma unroll
            for (int j = 0; j < 4; ++j) O[i][j] *= al;
        }
        __syncthreads();
        if (t < 64) {
            float ts = red[t][0];
            #pragma unroll
            for (int j = 1; j < 16; ++j) ts += red[t][j];
            lstate[t] = lstate[t] * alpha_s[t] + ts;
        }
        // ---- PV: O[i][j] += P[r][c] * V[c][d] ----
        #pragma unroll
        for (int c = 0; c < 64; ++c) {
            float4 pv = *(const float4*)&kpT[c][ty * 4];
            float4 vv = *(const float4*)&vS[c][tx * 4];
            const float* pa = (const float*)&pv;
            const float* va = (const float*)&vv;
            #pragma unroll
            for (int i = 0; i < 4; ++i)
                #pragma unroll
                for (int j = 0; j < 4; ++j)
                    O[i][j] = fmaf(pa[i], va[j], O[i][j]);
        }
    }
    __syncthreads();
    const int bb = bh / Hq, hh = bh % Hq;
    #pragma unroll
    for (int i = 0; i < 4; ++i) {
        const int r = ty * 4 + i;
        const float il = 1.0f / lstate[r];
        const int srow = qt * 64 + r;
        const int oidx = (bb * Sq + srow) * Cq + hh * 64 + tx * 4;
        *(float4*)&attn[oidx] = make_float4(O[i][0] * il, O[i][1] * il,
                                            O[i][2] * il, O[i][3] * il);
    }
}

// ---------------------------------------------------------------------------
extern "C" void kernel_launch(void* const* d_in, const int* in_sizes, int n_in,
                              void* d_out, int out_size, void* d_ws, size_t ws_size,
                              hipStream_t stream) {
    const float* x     = (const float*)d_in[0];
    const float* Wqkv  = (const float*)d_in[1];
    const float* Wproj = (const float*)d_in[2];
    const float* bproj = (const float*)d_in[3];
    float* out = (float*)d_out;
    float* ws  = (float*)d_ws;

    const size_t BHSD = (size_t)Bq * Hq * Sq * Dq;   // 3,145,728
    float* qbuf = ws;
    float* kbuf = ws + BHSD;
    float* vbuf = ws + 2 * BHSD;
    float* attn = ws + 3 * BHSD;
    float* ctab = ws + 4 * BHSD;
    float* stab = ctab + (size_t)Sq * 32;
    // total ws use: ~48.5 MB

    freq_kernel<<<256, 256, 0, stream>>>(ctab, stab);
    gemm_kernel<0><<<dim3(18, 32), 256, 0, stream>>>(x, Wqkv, qbuf, kbuf, vbuf,
                                                     ctab, stab, nullptr);
    attn_kernel<<<dim3(32, 24), 256, 0, stream>>>(qbuf, kbuf, vbuf, attn);
    gemm_kernel<1><<<dim3(6, 32), 256, 0, stream>>>(attn, Wproj, out, nullptr, nullptr,
                                                    nullptr, nullptr, bproj);
}

// Round 2
// 735.397 us; speedup vs baseline: 1.1253x; 1.1253x over previous
//
#include <hip/hip_runtime.h>
#include <math.h>

// Problem constants
#define Bq 2
#define Sq 2048
#define Cq 768
#define Hq 12
#define Dq 64

typedef __bf16 bfv8 __attribute__((ext_vector_type(8)));
typedef float f32x4 __attribute__((ext_vector_type(4)));
#define MFMA16(a, b, c) __builtin_amdgcn_mfma_f32_16x16x32_bf16(a, b, c, 0, 0, 0)

static __device__ inline unsigned short bfbits(float x) {
    __bf16 b = (__bf16)x;
    return __builtin_bit_cast(unsigned short, b);
}
static __device__ inline float bf2f(unsigned short b) {
    return (float)__builtin_bit_cast(__bf16, b);
}
static __device__ inline unsigned short lobits(float x, unsigned short hb) {
    return bfbits(x - bf2f(hb));
}

// ---------------------------------------------------------------------------
// Kernel 0: RoPE cos/sin tables  [S][32] each, fp64-accurate
// ---------------------------------------------------------------------------
__global__ void freq_kernel(float* __restrict__ ctab, float* __restrict__ stab) {
    int idx = blockIdx.x * blockDim.x + threadIdx.x;   // 0..65535
    int s = idx >> 5;
    int i = idx & 31;
    double f = (double)s * exp(-(double)i * 0.28782313662425573); // ln(1e4)/32
    ctab[idx] = (float)cos(f);
    stab[idx] = (float)sin(f);
}

// ---------------------------------------------------------------------------
// Tiled fp32 NT GEMM: out[m][n] = sum_k A[m][k] * B[n][k],  K = 768
// 128x128 tile, BK=16, 256 threads, 8x8 micro-tile per thread.
// MODE 0: QKV + fused RoPE -> writes bf16 hi/lo splits:
//         q,k in [B,H,S,D]; v transposed in [B,H,D,S]
// MODE 1: proj + bias -> fp32 [M][768] (= final output)
// ---------------------------------------------------------------------------
template <int MODE>
__global__ __launch_bounds__(256) void gemm_kernel(
    const float* __restrict__ A, const float* __restrict__ Bm,
    const float* __restrict__ ctab, const float* __restrict__ stab,
    unsigned short* __restrict__ qhb, unsigned short* __restrict__ qlb,
    unsigned short* __restrict__ khb, unsigned short* __restrict__ klb,
    unsigned short* __restrict__ vThb, unsigned short* __restrict__ vTlb,
    float* __restrict__ out0, const float* __restrict__ bias)
{
    __shared__ float aT[16][132];   // aT[k][m]
    __shared__ float bT[16][132];   // bT[k][n]

    const int t  = threadIdx.x;
    const int tx = t & 15;          // 0..15 -> n
    const int ty = t >> 4;          // 0..15 -> m
    const int lrow = t >> 1;        // 0..127 (row of tile being loaded)
    const int kq   = (t & 1) * 8;   // 0 or 8

    const int mBase = blockIdx.y * 128;
    const int nBase = blockIdx.x * 128;

    const float* Ap = A  + (mBase + lrow) * Cq + kq;
    const float* Bp = Bm + (nBase + lrow) * Cq + kq;

    float acc[8][8] = {};

    for (int k0 = 0; k0 < Cq; k0 += 16) {
        float4 a0 = *(const float4*)(Ap + k0);
        float4 a1 = *(const float4*)(Ap + k0 + 4);
        float4 b0 = *(const float4*)(Bp + k0);
        float4 b1 = *(const float4*)(Bp + k0 + 4);
        __syncthreads();   // previous compute finished reading LDS
        aT[kq + 0][lrow] = a0.x; aT[kq + 1][lrow] = a0.y;
        aT[kq + 2][lrow] = a0.z; aT[kq + 3][lrow] = a0.w;
        aT[kq + 4][lrow] = a1.x; aT[kq + 5][lrow] = a1.y;
        aT[kq + 6][lrow] = a1.z; aT[kq + 7][lrow] = a1.w;
        bT[kq + 0][lrow] = b0.x; bT[kq + 1][lrow] = b0.y;
        bT[kq + 2][lrow] = b0.z; bT[kq + 3][lrow] = b0.w;
        bT[kq + 4][lrow] = b1.x; bT[kq + 5][lrow] = b1.y;
        bT[kq + 6][lrow] = b1.z; bT[kq + 7][lrow] = b1.w;
        __syncthreads();
        #pragma unroll
        for (int kk = 0; kk < 16; ++kk) {
            float ar[8], br[8];
            *(float4*)&ar[0] = *(const float4*)&aT[kk][ty * 4];
            *(float4*)&ar[4] = *(const float4*)&aT[kk][64 + ty * 4];
            *(float4*)&br[0] = *(const float4*)&bT[kk][tx * 4];
            *(float4*)&br[4] = *(const float4*)&bT[kk][64 + tx * 4];
            #pragma unroll
            for (int i = 0; i < 8; ++i)
                #pragma unroll
                for (int j = 0; j < 8; ++j)
                    acc[i][j] = fmaf(ar[i], br[j], acc[i][j]);
        }
    }

    if (MODE == 0) {
        const int which = nBase / Cq;   // 0=q 1=k 2=v (128 | 768 -> uniform)
        #pragma unroll
        for (int ig = 0; ig < 2; ++ig) {
            #pragma unroll
            for (int jg = 0; jg < 2; ++jg) {
                const int cbase = nBase + jg * 64 + tx * 4;
                const int rem   = cbase - which * Cq;
                const int h     = rem >> 6;
                const int dd    = rem & 63;           // aligned to 4
                #pragma unroll
                for (int i = 0; i < 4; ++i) {
                    const int rg = mBase + ig * 64 + ty * 4 + i;
                    const int bb = rg >> 11;
                    const int ss = rg & 2047;
                    float v0 = acc[ig * 4 + i][jg * 4 + 0];
                    float v1 = acc[ig * 4 + i][jg * 4 + 1];
                    float v2 = acc[ig * 4 + i][jg * 4 + 2];
                    float v3 = acc[ig * 4 + i][jg * 4 + 3];
                    float o0, o1, o2, o3;
                    if (which < 2) {
                        const int fi = ss * 32 + (dd >> 1);
                        float c0 = ctab[fi],     s0 = stab[fi];
                        float c1 = ctab[fi + 1], s1 = stab[fi + 1];
                        o0 = v0 * c0 - v1 * s0;  o1 = v1 * c0 + v0 * s0;
                        o2 = v2 * c1 - v3 * s1;  o3 = v3 * c1 + v2 * s1;
                    } else {
                        o0 = v0; o1 = v1; o2 = v2; o3 = v3;
                    }
                    unsigned short h0 = bfbits(o0), h1 = bfbits(o1),
                                   h2 = bfbits(o2), h3 = bfbits(o3);
                    unsigned short l0 = lobits(o0, h0), l1 = lobits(o1, h1),
                                   l2 = lobits(o2, h2), l3 = lobits(o3, h3);
                    if (which < 2) {
                        const size_t oidx = ((size_t)(bb * Hq + h) * Sq + ss) * Dq + dd;
                        unsigned short* hp = (which == 0) ? qhb : khb;
                        unsigned short* lp = (which == 0) ? qlb : klb;
                        *(ushort4*)&hp[oidx] = make_ushort4(h0, h1, h2, h3);
                        *(ushort4*)&lp[oidx] = make_ushort4(l0, l1, l2, l3);
                    } else {
                        // v transposed: [B,H,D,S]
                        const size_t base = (size_t)(bb * Hq + h) * Dq;
                        vThb[(base + dd + 0) * Sq + ss] = h0;
                        vThb[(base + dd + 1) * Sq + ss] = h1;
                        vThb[(base + dd + 2) * Sq + ss] = h2;
                        vThb[(base + dd + 3) * Sq + ss] = h3;
                        vTlb[(base + dd + 0) * Sq + ss] = l0;
                        vTlb[(base + dd + 1) * Sq + ss] = l1;
                        vTlb[(base + dd + 2) * Sq + ss] = l2;
                        vTlb[(base + dd + 3) * Sq + ss] = l3;
                    }
                }
            }
        }
    } else {
        #pragma unroll
        for (int ig = 0; ig < 2; ++ig) {
            #pragma unroll
            for (int jg = 0; jg < 2; ++jg) {
                const int cbase = nBase + jg * 64 + tx * 4;
                float4 bz = *(const float4*)&bias[cbase];
                #pragma unroll
                for (int i = 0; i < 4; ++i) {
                    const int rg = mBase + ig * 64 + ty * 4 + i;
                    float4 r = make_float4(acc[ig*4+i][jg*4+0] + bz.x,
                                           acc[ig*4+i][jg*4+1] + bz.y,
                                           acc[ig*4+i][jg*4+2] + bz.z,
                                           acc[ig*4+i][jg*4+3] + bz.w);
                    *(float4*)&out0[(size_t)rg * Cq + cbase] = r;
                }
            }
        }
    }
}

// ---------------------------------------------------------------------------
// Kernel 2: MFMA flash attention, bf16 3-term split (hi*hi + hi*lo + lo*hi).
// Block = 4 waves; wave w owns q-rows [qt*64 + w*16, +16). K-tile = 64 keys.
// A/B fragments load straight from global (16B each); only P transits LDS.
// ---------------------------------------------------------------------------
__global__ __launch_bounds__(256) void attn_mfma_kernel(
    const unsigned short* __restrict__ qhb, const unsigned short* __restrict__ qlb,
    const unsigned short* __restrict__ khb, const unsigned short* __restrict__ klb,
    const unsigned short* __restrict__ vThb, const unsigned short* __restrict__ vTlb,
    float* __restrict__ attn)
{
    __shared__ unsigned int pbuf[4][16][68];   // per-wave P tile, (lo<<16)|hi

    const int t    = threadIdx.x;
    const int w    = t >> 6;
    const int lane = t & 63;
    const int ml   = lane & 15;
    const int quad = lane >> 4;
    const int qt = blockIdx.x;      // 0..31
    const int bh = blockIdx.y;      // 0..23

    // ---- Q fragments (A-layout): row m=ml, k = ks*32 + quad*8 + j ----
    const size_t qoff = ((size_t)bh * Sq + qt * 64 + w * 16 + ml) * Dq + quad * 8;
    bfv8 aQh[2], aQl[2];
    #pragma unroll
    for (int ks = 0; ks < 2; ++ks) {
        aQh[ks] = *(const bfv8*)(qhb + qoff + ks * 32);
        aQl[ks] = *(const bfv8*)(qlb + qoff + ks * 32);
    }

    float m_st[4], l_st[4];
    f32x4 O[4];
    #pragma unroll
    for (int r = 0; r < 4; ++r) { m_st[r] = -INFINITY; l_st[r] = 0.f; }
    #pragma unroll
    for (int ng = 0; ng < 4; ++ng) O[ng] = (f32x4){0.f, 0.f, 0.f, 0.f};

    for (int kt = 0; kt < 32; ++kt) {
        // ---- scores S = Q K^T : B-frag n = key, k = d ----
        f32x4 S[4];
        const size_t kbase = ((size_t)bh * Sq + kt * 64) * Dq + quad * 8;
        #pragma unroll
        for (int ng = 0; ng < 4; ++ng) {
            f32x4 acc = (f32x4){0.f, 0.f, 0.f, 0.f};
            #pragma unroll
            for (int ks = 0; ks < 2; ++ks) {
                const size_t ko = kbase + (size_t)(ng * 16 + ml) * Dq + ks * 32;
                bfv8 bKh = *(const bfv8*)(khb + ko);
                bfv8 bKl = *(const bfv8*)(klb + ko);
                acc = MFMA16(aQh[ks], bKh, acc);
                acc = MFMA16(aQl[ks], bKh, acc);
                acc = MFMA16(aQh[ks], bKl, acc);
            }
            S[ng] = acc;
        }

        // ---- online softmax (rows = quad*4 + r, cols across 16 lanes) ----
        float nm[4], alpha[4];
        #pragma unroll
        for (int r = 0; r < 4; ++r) {
            float mx = fmaxf(fmaxf(S[0][r], S[1][r]), fmaxf(S[2][r], S[3][r])) * 0.125f;
            #pragma unroll
            for (int off = 1; off < 16; off <<= 1)
                mx = fmaxf(mx, __shfl_xor(mx, off, 64));
            nm[r] = fmaxf(m_st[r], mx);
            alpha[r] = __expf(m_st[r] - nm[r]);
            m_st[r] = nm[r];
        }
        float ps[4] = {0.f, 0.f, 0.f, 0.f};
        #pragma unroll
        for (int ng = 0; ng < 4; ++ng) {
            #pragma unroll
            for (int r = 0; r < 4; ++r) {
                float p = __expf(S[ng][r] * 0.125f - nm[r]);
                ps[r] += p;
                unsigned short ph = bfbits(p);
                unsigned short pl = lobits(p, ph);
                pbuf[w][quad * 4 + r][ng * 16 + ml] =
                    (unsigned int)ph | ((unsigned int)pl << 16);
            }
        }
        #pragma unroll
        for (int r = 0; r < 4; ++r) {
            #pragma unroll
            for (int off = 1; off < 16; off <<= 1)
                ps[r] += __shfl_xor(ps[r], off, 64);
            l_st[r] = l_st[r] * alpha[r] + ps[r];
            O[0][r] *= alpha[r]; O[1][r] *= alpha[r];
            O[2][r] *= alpha[r]; O[3][r] *= alpha[r];
        }

        // ---- read P back as A-frags (wave-private LDS, DS pipe in-order) ----
        bfv8 aPh[2], aPl[2];
        #pragma unroll
        for (int ks = 0; ks < 2; ++ks) {
            const unsigned int* src = &pbuf[w][ml][ks * 32 + quad * 8];
            uint4 w0 = *(const uint4*)src;
            uint4 w1 = *(const uint4*)(src + 4);
            union { unsigned short s[8]; bfv8 v; } hu, lu;
            unsigned int arr[8] = {w0.x, w0.y, w0.z, w0.w, w1.x, w1.y, w1.z, w1.w};
            #pragma unroll
            for (int j = 0; j < 8; ++j) {
                hu.s[j] = (unsigned short)(arr[j] & 0xffffu);
                lu.s[j] = (unsigned short)(arr[j] >> 16);
            }
            aPh[ks] = hu.v;
            aPl[ks] = lu.v;
        }

        // ---- O += P V : B-frag n = d (vT[d][key]), k = key ----
        const size_t vbase = (size_t)bh * Dq * Sq + kt * 64 + quad * 8;
        #pragma unroll
        for (int ng = 0; ng < 4; ++ng) {
            #pragma unroll
            for (int ks = 0; ks < 2; ++ks) {
                const size_t vo = vbase + (size_t)(ng * 16 + ml) * Sq + ks * 32;
                bfv8 bVh = *(const bfv8*)(vThb + vo);
                bfv8 bVl = *(const bfv8*)(vTlb + vo);
                O[ng] = MFMA16(aPh[ks], bVh, O[ng]);
                O[ng] = MFMA16(aPl[ks], bVh, O[ng]);
                O[ng] = MFMA16(aPh[ks], bVl, O[ng]);
            }
        }
    }

    // ---- epilogue: O /= l, write [B,S,C] fp32 ----
    const int bb = bh / Hq, hh = bh % Hq;
    #pragma unroll
    for (int r = 0; r < 4; ++r) {
        const float il = 1.0f / l_st[r];
        const int srow = qt * 64 + w * 16 + quad * 4 + r;
        const size_t obase = ((size_t)bb * Sq + srow) * Cq + hh * 64 + ml;
        #pragma unroll
        for (int ng = 0; ng < 4; ++ng)
            attn[obase + ng * 16] = O[ng][r] * il;
    }
}

// ---------------------------------------------------------------------------
extern "C" void kernel_launch(void* const* d_in, const int* in_sizes, int n_in,
                              void* d_out, int out_size, void* d_ws, size_t ws_size,
                              hipStream_t stream) {
    const float* x     = (const float*)d_in[0];
    const float* Wqkv  = (const float*)d_in[1];
    const float* Wproj = (const float*)d_in[2];
    const float* bproj = (const float*)d_in[3];
    float* out = (float*)d_out;

    const size_t BHSD = (size_t)Bq * Hq * Sq * Dq;   // 3,145,728
    char* p = (char*)d_ws;
    unsigned short* qhb  = (unsigned short*)p; p += BHSD * 2;
    unsigned short* qlb  = (unsigned short*)p; p += BHSD * 2;
    unsigned short* khb  = (unsigned short*)p; p += BHSD * 2;
    unsigned short* klb  = (unsigned short*)p; p += BHSD * 2;
    unsigned short* vThb = (unsigned short*)p; p += BHSD * 2;
    unsigned short* vTlb = (unsigned short*)p; p += BHSD * 2;
    float* attn = (float*)p; p += BHSD * 4;
    float* ctab = (float*)p; p += (size_t)Sq * 32 * 4;
    float* stab = (float*)p; p += (size_t)Sq * 32 * 4;
    // total ws use ~51 MB

    freq_kernel<<<256, 256, 0, stream>>>(ctab, stab);
    gemm_kernel<0><<<dim3(18, 32), 256, 0, stream>>>(
        x, Wqkv, ctab, stab, qhb, qlb, khb, klb, vThb, vTlb, nullptr, nullptr);
    attn_mfma_kernel<<<dim3(32, 24), 256, 0, stream>>>(
        qhb, qlb, khb, klb, vThb, vTlb, attn);
    gemm_kernel<1><<<dim3(6, 32), 256, 0, stream>>>(
        attn, Wproj, ctab, stab, nullptr, nullptr, nullptr, nullptr, nullptr, nullptr,
        out, bproj);
}